// Round 7
// baseline (335.588 us; speedup 1.0000x reference)
//
#include <hip/hip_runtime.h>

typedef __attribute__((ext_vector_type(8))) __bf16 bf16x8;
typedef __attribute__((ext_vector_type(4))) float f32x4;

typedef __attribute__((address_space(3))) unsigned int as3u32;
typedef __attribute__((address_space(1))) const unsigned int as1u32;

__device__ __forceinline__ bf16x8 cvt8(f32x4 a, f32x4 b) {
    bf16x8 v;
    v[0] = (__bf16)a.x; v[1] = (__bf16)a.y; v[2] = (__bf16)a.z; v[3] = (__bf16)a.w;
    v[4] = (__bf16)b.x; v[5] = (__bf16)b.y; v[6] = (__bf16)b.z; v[7] = (__bf16)b.w;
    return v;
}

// ---------------------------------------------------------------------------
// Kernel 0: zero 512KB accumulator + build graph offsets from sorted batch.
// ---------------------------------------------------------------------------
__global__ void prep(const int* __restrict__ batch, int nN,
                     float* __restrict__ sums, int* __restrict__ off)
{
    const int i = blockIdx.x * blockDim.x + threadIdx.x;
    const int stride = gridDim.x * blockDim.x;
    for (int t = i; t < 1024 * 128; t += stride) sums[t] = 0.f;
    for (int t = i; t < nN; t += stride) {
        const int b  = batch[t];
        const int bp = (t == 0) ? -1 : batch[t - 1];
        for (int g = bp + 1; g <= b; ++g) off[g] = t;
        if (t == nN - 1) {
            for (int g = b + 1; g <= 1024; ++g) off[g] = nN;
        }
    }
}

// ---------------------------------------------------------------------------
// Kernel 1: 512 thr / 8 waves, 32-row tiles, ~34KB LDS -> 4 blocks/CU at
// <=64 VGPR (launch_bounds(512,8)). Wave w owns cols [16w,16w+16) of both
// states and gates. x staged f32 via global_load_lds (no staging VGPRs),
// double-buffered, source-pre-swizzled 16B XOR, f32->bf16 at fragment read.
// Two raw barriers per tile. Per-graph column sums in registers; atomics
// only at graph boundaries.
// ---------------------------------------------------------------------------
__global__ __launch_bounds__(512, 8) void gnn_main(
    const float* __restrict__ x, const int* __restrict__ batch,
    const float* __restrict__ Wlin, const float* __restrict__ blin,
    const float* __restrict__ Wgate, const float* __restrict__ bgate,
    float* __restrict__ sums, int nN, int P)
{
    __shared__ float bufA[2][32 * 128];   // 2 x 16 KB f32, 16B-XOR swizzled
    __shared__ float PS[8][36];           // per-wave row partial sums (padded)
    __shared__ float invLds[32];          // per-row 1/sum

    const int tid  = threadIdx.x;
    const int lane = tid & 63;
    const int w    = tid >> 6;    // wave 0..7
    const int l15  = lane & 15;
    const int lg   = lane >> 4;   // 0..3

    const int R0 = blockIdx.x * P;
    if (R0 >= nN) return;
    const int R1b = min(R0 + P, nN);
    const int nt  = (R1b - R0 + 31) >> 5;

    // ---- W fragments (B operand): rows [16w,16w+16) of Wlin / Wgate
    bf16x8 bfrag[2][4];
    {
        const float* Wp0 = Wlin  + (size_t)(w * 16 + l15) * 128 + lg * 8;
        const float* Wp1 = Wgate + (size_t)(w * 16 + l15) * 128 + lg * 8;
#pragma unroll
        for (int kk = 0; kk < 4; ++kk) {
            bfrag[0][kk] = cvt8(*(const f32x4*)(Wp0 + kk * 32),
                                *(const f32x4*)(Wp0 + kk * 32 + 4));
            bfrag[1][kk] = cvt8(*(const f32x4*)(Wp1 + kk * 32),
                                *(const f32x4*)(Wp1 + kk * 32 + 4));
        }
    }
    const float bl = blin[w * 16 + l15];
    const float bg = bgate[w * 16 + l15];

    // ---- staging: LDS dest linear, global source pre-swizzled so that
    // LDS[row][b] = x[row][b ^ ((row&7)<<4)]; 2 x 16B per thread per tile
    const int srh = tid >> 5;          // row within 16-row group (0..15)
    const int sb  = (tid & 31) * 16;   // byte within 512B row
    int btn;
    auto STAGE = [&](int bsel, int base) {
#pragma unroll
        for (int i = 0; i < 2; ++i) {
            const int row = i * 16 + srh;
            const int nd  = base + row;
            const int ndc = nd < nN ? nd : nN - 1;
            const int bsw = sb ^ ((row & 7) << 4);
            const float* src = x + (size_t)ndc * 128 + (bsw >> 2);
            char* dst = (char*)&bufA[bsel][0] + i * 8192 + tid * 16;
            __builtin_amdgcn_global_load_lds((as1u32*)src, (as3u32*)dst, 16, 0, 0);
        }
        const int bi = base + lane;
        btn = (bi < nN) ? batch[bi] : -1;
    };

    float racc = 0.f;
    int   gcur = batch[R0];
    auto flush = [&](int g) {
        float v = racc;
        v += __shfl_xor(v, 16);
        v += __shfl_xor(v, 32);
        if (lg == 0) atomicAdd(sums + (size_t)g * 128 + w * 16 + l15, v);
        racc = 0.f;
    };

    // ---- prologue
    STAGE(0, R0);
    int bt = btn;
    asm volatile("s_waitcnt vmcnt(0)\n\ts_barrier" ::: "memory");

    for (int t = 0; t < nt; ++t) {
        const int base = R0 + (t << 5);
        const bool more = (t + 1 < nt);
        if (more) STAGE((t + 1) & 1, base + 32);   // in flight through GEMMs

        // ---- fused dual GEMM from f32 LDS tile (convert per fragment)
        f32x4 accS[2], accG[2];
#pragma unroll
        for (int r16 = 0; r16 < 2; ++r16) { accS[r16] = (f32x4)0.f; accG[r16] = (f32x4)0.f; }
        const char* bc = (const char*)&bufA[t & 1][0];
#pragma unroll
        for (int kk = 0; kk < 4; ++kk) {
#pragma unroll
            for (int r16 = 0; r16 < 2; ++r16) {
                const int row = r16 * 16 + l15;
                const int sw  = (row & 7) << 4;
                const int byt = row * 512 + kk * 128 + lg * 32;
                f32x4 u0 = *(const f32x4*)(bc + ((byt) ^ sw));
                f32x4 u1 = *(const f32x4*)(bc + ((byt + 16) ^ sw));
                bf16x8 af = cvt8(u0, u1);
                accS[r16] = __builtin_amdgcn_mfma_f32_16x16x32_bf16(af, bfrag[0][kk], accS[r16], 0, 0, 0);
                accG[r16] = __builtin_amdgcn_mfma_f32_16x16x32_bf16(af, bfrag[1][kk], accG[r16], 0, 0, 0);
            }
        }

        // ---- exp + per-wave row partials (reduce over l15) -> PS
#pragma unroll
        for (int r16 = 0; r16 < 2; ++r16) {
            f32x4 p;
#pragma unroll
            for (int r = 0; r < 4; ++r) {
                float e = __expf(accG[r16][r] + bg);
                accG[r16][r] = e;
                p[r] = e;
            }
#pragma unroll
            for (int d = 1; d <= 8; d <<= 1) {
#pragma unroll
                for (int r = 0; r < 4; ++r) p[r] += __shfl_xor(p[r], d);
            }
            if (l15 == 0) *(f32x4*)&PS[w][r16 * 16 + lg * 4] = p;
        }
        asm volatile("s_waitcnt lgkmcnt(0)\n\ts_barrier" ::: "memory");  // B1

        // ---- stage 2: total row sums (wave w -> rows [4w,4w+4))
        {
            const int p   = lane & 7;            // partial index over 8 waves
            const int rw  = w * 4 + (lane >> 4); // this lane's row
            float v = PS[p][rw];
            v += __shfl_xor(v, 1);
            v += __shfl_xor(v, 2);
            v += __shfl_xor(v, 4);
            if ((lane & 15) == 0) invLds[rw] = 1.0f / v;
        }
        // B2: invLds visible AND next f32 tile fully landed in LDS
        asm volatile("s_waitcnt vmcnt(0) lgkmcnt(0)\n\ts_barrier" ::: "memory");

        // ---- gating
#pragma unroll
        for (int r16 = 0; r16 < 2; ++r16) {
            f32x4 iv = *(const f32x4*)&invLds[r16 * 16 + lg * 4];
#pragma unroll
            for (int r = 0; r < 4; ++r)
                accS[r16][r] = (accS[r16][r] + bl) * accG[r16][r] * iv[r];
        }

        // ---- segmented per-graph accumulation (rows base..base+31, sorted)
        const int nvalid = min(32, nN - base);
        const int gf = __shfl(bt, 0);
        const int gl = __shfl(bt, nvalid - 1);
        if (nvalid == 32 && gf == gl) {
            if (gf != gcur) { flush(gcur); gcur = gf; }
            float ts = 0.f;
#pragma unroll
            for (int r16 = 0; r16 < 2; ++r16)
#pragma unroll
                for (int r = 0; r < 4; ++r) ts += accS[r16][r];
            racc += ts;
        } else {
            for (int g = gf; g <= gl; ++g) {
                float cs = 0.f;
#pragma unroll
                for (int r16 = 0; r16 < 2; ++r16)
#pragma unroll
                    for (int r = 0; r < 4; ++r) {
                        const int bid = __shfl(bt, r16 * 16 + lg * 4 + r);
                        cs += (bid == g) ? accS[r16][r] : 0.f;
                    }
                if (g == gcur) racc += cs;
                else { flush(gcur); gcur = g; racc = cs; }
            }
        }
        bt = btn;
    }
    flush(gcur);
}

// ---------------------------------------------------------------------------
// Kernel 2: mean = sums/count, out = mean @ Wf^T + bf
// ---------------------------------------------------------------------------
__global__ __launch_bounds__(128) void final_mm(
    const float* __restrict__ sums, const int* __restrict__ off,
    const float* __restrict__ Wf, const float* __restrict__ bf,
    float* __restrict__ out)
{
    const int g = blockIdx.x, c = threadIdx.x;
    __shared__ float m[128];
    const int cnt = off[g + 1] - off[g];
    const float invC = 1.0f / (float)(cnt > 0 ? cnt : 1);
    m[c] = sums[g * 128 + c] * invC;
    __syncthreads();
    float acc = bf[c];
    const f32x4* wr = (const f32x4*)(Wf + (size_t)c * 128);
#pragma unroll
    for (int k = 0; k < 32; ++k) {
        f32x4 wv = wr[k];
        acc += m[4 * k] * wv.x + m[4 * k + 1] * wv.y + m[4 * k + 2] * wv.z + m[4 * k + 3] * wv.w;
    }
    out[g * 128 + c] = acc;
}

extern "C" void kernel_launch(void* const* d_in, const int* in_sizes, int n_in,
                              void* d_out, int out_size, void* d_ws, size_t ws_size,
                              hipStream_t stream)
{
    const float* x     = (const float*)d_in[0];
    const int*   batch = (const int*)d_in[1];
    const float* Wlin  = (const float*)d_in[2];
    const float* blin  = (const float*)d_in[3];
    const float* Wgate = (const float*)d_in[4];
    const float* bgate = (const float*)d_in[5];
    const float* Wfin  = (const float*)d_in[6];
    const float* bfin  = (const float*)d_in[7];
    float* out  = (float*)d_out;
    float* sums = (float*)d_ws;                               // 512 KB
    int*   off  = (int*)((char*)d_ws + 512 * 1024);           // 1025 ints

    const int nNodes  = in_sizes[1];
    const int nGraphs = out_size / 128;

    // ~977 blocks (4 resident/CU target), contiguous ranges, P multiple of 32
    const int P  = ((((nNodes + 1023) / 1024) + 31) & ~31);
    const int nB = (nNodes + P - 1) / P;

    prep<<<2048, 256, 0, stream>>>(batch, nNodes, sums, off);
    gnn_main<<<nB, 512, 0, stream>>>(x, batch, Wlin, blin, Wgate, bgate, sums, nNodes, P);
    final_mm<<<nGraphs, 128, 0, stream>>>(sums, off, Wfin, bfin, out);
}